// Round 1
// baseline (764.712 us; speedup 1.0000x reference)
//
#include <hip/hip_runtime.h>

// Cross-attention with value amplification, fully refactored:
//   A_bT[b][n=g*160+hl*77+j][k<320]  = scale * Wq[k][h*40+d] . K_b[j][h*40+d]   (bf16)
//   C_bT[b][n2<320][kk=g*160+hl*77+j]= V_b[j][h*40+d] . Wo[h*40+d][n2]          (bf16)
//   S = hs @ A  -> per-head softmax -> out = P @ C + bo + residual
// Main kernel: 64-row tiles, 4 head-groups of 2 heads (panel N=160), MFMA 16x16x32 bf16.

typedef __attribute__((ext_vector_type(8))) short short8_t;
typedef __attribute__((ext_vector_type(4))) float f32x4;

#define NBATCH 4
#define SQ     16384
#define CDIM   320
#define SKV    77
#define CXDIM  768
#define NHEAD  8
#define DHEAD  40
#define NGRP   4
#define PN     160      // panel cols per group (2*77 padded to 160)
#define HS_STRIDE 328   // 320 + 8 pad (keeps 16B align, breaks bank pattern)
#define SP_STRIDE 168   // 160 + 8 pad

// ws layout (bytes)
#define K_OFF 0
#define V_OFF 394240
#define A_OFF 788480
#define C_OFF 2426880
// total needed: 4065280 bytes

__device__ __forceinline__ ushort f2bf(float f) {
  union { float f; unsigned u; } x; x.f = f;
  unsigned u = x.u;
  return (ushort)((u + 0x7FFFu + ((u >> 16) & 1u)) >> 16);   // RNE, no NaN in data
}
__device__ __forceinline__ float bf2f(ushort h) {
  union { unsigned u; float f; } x; x.u = ((unsigned)h) << 16;
  return x.f;
}

// ---------------- P1: K/V projection (+ amplification on V) ----------------
// grid 160 = kv(2) x b(4) x colchunk(20x16), 512 threads
__global__ __launch_bounds__(512) void kv_proj(
    const float* __restrict__ ehs, const float* __restrict__ Wk,
    const float* __restrict__ Wv, const int* __restrict__ tstep,
    float* __restrict__ Kws, float* __restrict__ Vws)
{
  int bx = blockIdx.x;
  int cc = bx % 20;
  int b  = (bx / 20) % 4;
  int kv = bx / 80;
  const float* W = kv ? Wv : Wk;
  float* O = kv ? Vws : Kws;

  int t = threadIdx.x;
  int c = cc * 16 + (t & 15);
  int slot = t >> 4;                       // 0..31
  float acc0 = 0.f, acc1 = 0.f, acc2 = 0.f;

  __shared__ float lds_e[SKV * 64];
  const float* esrc = ehs + (size_t)b * SKV * CXDIM;

  for (int dt = 0; dt < 12; ++dt) {
    __syncthreads();
    for (int i = t; i < SKV * 64; i += 512) {
      int s = i >> 6, dl = i & 63;
      lds_e[i] = esrc[(size_t)s * CXDIM + dt * 64 + dl];
    }
    __syncthreads();
    #pragma unroll 8
    for (int dl = 0; dl < 64; ++dl) {
      float wv = W[(size_t)(dt * 64 + dl) * CDIM + c];
      acc0 += lds_e[(slot << 6) + dl] * wv;
      acc1 += lds_e[((slot + 32) << 6) + dl] * wv;
      if (slot < 13) acc2 += lds_e[((slot + 64) << 6) + dl] * wv;
    }
  }

  float amp = fmaxf(1.0f, (float)(tstep[0] - 1) * 0.02f);
  float accs[3] = {acc0, acc1, acc2};
  #pragma unroll
  for (int k = 0; k < 3; ++k) {
    int s = slot + 32 * k;
    if (s < SKV) {
      float v = accs[k];
      if (kv && (b == 1 || b == 3) && (s == 2 || s == 5)) v *= amp;
      O[((size_t)(b * SKV + s)) * CDIM + c] = v;
    }
  }
}

// ---------------- P2: A_bT = scale * K_bh @ Wq_h^T ----------------
// grid 320 = b(4) x h(8) x kchunk(10x32), 256 threads
__global__ __launch_bounds__(256) void build_A(
    const float* __restrict__ Kws, const float* __restrict__ Wq,
    ushort* __restrict__ Aws)
{
  int bx = blockIdx.x;
  int kc = bx % 10;
  int h  = (bx / 10) % 8;
  int b  = bx / 80;
  int t = threadIdx.x;
  int kcol = kc * 32 + (t & 31);
  int jslot = t >> 5;                      // 0..7

  __shared__ float lds_k[SKV * DHEAD];
  for (int i = t; i < SKV * DHEAD; i += 256) {
    int j = i / DHEAD, d = i % DHEAD;
    lds_k[i] = Kws[((size_t)(b * SKV + j)) * CDIM + h * DHEAD + d];
  }
  __syncthreads();

  float wq[DHEAD];
  #pragma unroll
  for (int d = 0; d < DHEAD; ++d)
    wq[d] = Wq[(size_t)kcol * CDIM + h * DHEAD + d] * 0.15811388f; // 1/sqrt(40)

  int g = h >> 1, hl = h & 1;
  #pragma unroll
  for (int m = 0; m < 10; ++m) {
    int j = jslot + 8 * m;
    if (j < SKV) {
      float a = 0.f;
      #pragma unroll
      for (int d = 0; d < DHEAD; ++d) a += wq[d] * lds_k[j * DHEAD + d];
      Aws[((size_t)(b * 640 + g * PN + hl * SKV + j)) * CDIM + kcol] = f2bf(a);
    }
  }
}

// ---------------- P3: C_bT = (V_bh @ Wo_h)^T ----------------
// grid 320 = b(4) x h(8) x n2chunk(10x32), 256 threads
__global__ __launch_bounds__(256) void build_C(
    const float* __restrict__ Vws, const float* __restrict__ Wo,
    ushort* __restrict__ Cws)
{
  int bx = blockIdx.x;
  int nc = bx % 10;
  int h  = (bx / 10) % 8;
  int b  = bx / 80;
  int t = threadIdx.x;
  int n2 = nc * 32 + (t & 31);
  int jslot = t >> 5;

  __shared__ float lds_v[SKV * DHEAD];
  for (int i = t; i < SKV * DHEAD; i += 256) {
    int j = i / DHEAD, d = i % DHEAD;
    lds_v[i] = Vws[((size_t)(b * SKV + j)) * CDIM + h * DHEAD + d];
  }
  __syncthreads();

  float acc[10];
  #pragma unroll
  for (int m = 0; m < 10; ++m) acc[m] = 0.f;

  for (int d = 0; d < DHEAD; ++d) {
    float wo = Wo[((size_t)(h * DHEAD + d)) * CDIM + n2];
    #pragma unroll
    for (int m = 0; m < 10; ++m) {
      int j = jslot + 8 * m;
      if (j < SKV) acc[m] += lds_v[j * DHEAD + d] * wo;
    }
  }
  int g = h >> 1, hl = h & 1;
  #pragma unroll
  for (int m = 0; m < 10; ++m) {
    int j = jslot + 8 * m;
    if (j < SKV)
      Cws[((size_t)(b * CDIM + n2)) * 640 + g * PN + hl * SKV + j] = f2bf(acc[m]);
  }
}

// ---------------- Main fused kernel ----------------
// grid 1024 = b(4) x rowtile(256 of 64 rows), 256 threads (4 waves, wave w owns rows 16w..16w+16)
__global__ __launch_bounds__(256, 2) void attn_main(
    const float* __restrict__ hs, const ushort* __restrict__ Aws,
    const ushort* __restrict__ Cws, const float* __restrict__ bo,
    float* __restrict__ out)
{
  __shared__ ushort lds_hs[64 * HS_STRIDE];
  __shared__ ushort lds_sp[64 * SP_STRIDE];

  int bx = blockIdx.x;
  int b = bx >> 8;
  int row0 = (bx & 255) << 6;
  int t = threadIdx.x;
  int w = t >> 6;
  int lane = t & 63;
  int l15 = lane & 15, l4 = lane >> 4;

  // ---- stage hs tile (f32 -> bf16) ----
  const float* hsrc = hs + ((size_t)(b * SQ + row0)) * CDIM;
  #pragma unroll
  for (int it = 0; it < 20; ++it) {
    int s = t + 256 * it;          // float4 index, 5120 total
    int r = s / 80, f = s % 80;
    float4 v = ((const float4*)hsrc)[s];
    ushort4 u;
    u.x = f2bf(v.x); u.y = f2bf(v.y); u.z = f2bf(v.z); u.w = f2bf(v.w);
    *(ushort4*)&lds_hs[r * HS_STRIDE + 4 * f] = u;
  }
  __syncthreads();

  f32x4 acc2[20];
  #pragma unroll
  for (int i = 0; i < 20; ++i) acc2[i] = (f32x4){0.f, 0.f, 0.f, 0.f};

  const int arow = (w * 16 + l15) * HS_STRIDE + l4 * 8;
  const int prow = (w * 16 + l15) * SP_STRIDE + l4 * 8;

  for (int g = 0; g < NGRP; ++g) {
    // ---- GEMM1: S[64][160] = hs_tile @ A_panel ----
    f32x4 acc1[10];
    #pragma unroll
    for (int i = 0; i < 10; ++i) acc1[i] = (f32x4){0.f, 0.f, 0.f, 0.f};

    const ushort* Bp = Aws + ((size_t)(b * 640 + g * PN)) * CDIM + (size_t)l15 * CDIM + l4 * 8;
    #pragma unroll
    for (int ks = 0; ks < 10; ++ks) {
      short8_t a = *(const short8_t*)&lds_hs[arow + ks * 32];
      #pragma unroll
      for (int nt = 0; nt < 10; ++nt) {
        short8_t bb = *(const short8_t*)&Bp[(size_t)nt * 16 * CDIM + ks * 32];
        acc1[nt] = __builtin_amdgcn_mfma_f32_16x16x32_bf16(a, bb, acc1[nt], 0, 0, 0);
      }
    }
    // write S to LDS (bf16)
    #pragma unroll
    for (int nt = 0; nt < 10; ++nt) {
      #pragma unroll
      for (int r = 0; r < 4; ++r)
        lds_sp[(w * 16 + l4 * 4 + r) * SP_STRIDE + nt * 16 + l15] = f2bf(acc1[nt][r]);
    }
    __syncthreads();

    // ---- softmax: thread -> (row=t>>2, head=(t>>1)&1, half=t&1), partner = t^1 ----
    {
      int row = t >> 2, hl = (t >> 1) & 1, half = t & 1;
      int base = row * SP_STRIDE + hl * SKV;
      int j0 = half ? 39 : 0;
      int j1 = half ? SKV : 39;
      float mx = -1e30f;
      for (int j = j0; j < j1; ++j) mx = fmaxf(mx, bf2f(lds_sp[base + j]));
      mx = fmaxf(mx, __shfl_xor(mx, 1));
      float sum = 0.f;
      for (int j = j0; j < j1; ++j) {
        float e = __expf(bf2f(lds_sp[base + j]) - mx);
        sum += e;
        lds_sp[base + j] = f2bf(e);
      }
      sum += __shfl_xor(sum, 1);
      float inv = 1.0f / sum;
      for (int j = j0; j < j1; ++j)
        lds_sp[base + j] = f2bf(bf2f(lds_sp[base + j]) * inv);
    }
    __syncthreads();

    // ---- GEMM2: out[64][320] += P_panel @ C_panel ----
    const ushort* Cp = Cws + (size_t)b * CDIM * 640 + g * PN + (size_t)l15 * 640 + l4 * 8;
    #pragma unroll
    for (int ks = 0; ks < 5; ++ks) {
      short8_t a2 = *(const short8_t*)&lds_sp[prow + ks * 32];
      #pragma unroll
      for (int nt = 0; nt < 20; ++nt) {
        short8_t b2 = *(const short8_t*)&Cp[(size_t)nt * 16 * 640 + ks * 32];
        acc2[nt] = __builtin_amdgcn_mfma_f32_16x16x32_bf16(a2, b2, acc2[nt], 0, 0, 0);
      }
    }
    __syncthreads();   // protect lds_sp before next group's S-write
  }

  // ---- epilogue: + bo + residual(f32), store ----
  #pragma unroll
  for (int nt = 0; nt < 20; ++nt) {
    int n0 = nt * 16 + l15;
    float bov = bo[n0];
    #pragma unroll
    for (int r = 0; r < 4; ++r) {
      int rowg = row0 + w * 16 + l4 * 4 + r;
      size_t oi = ((size_t)(b * SQ + rowg)) * CDIM + n0;
      out[oi] = acc2[nt][r] + bov + hs[oi];
    }
  }
}

extern "C" void kernel_launch(void* const* d_in, const int* in_sizes, int n_in,
                              void* d_out, int out_size, void* d_ws, size_t ws_size,
                              hipStream_t stream) {
  const float* hs  = (const float*)d_in[0];
  const float* ehs = (const float*)d_in[1];
  const float* Wq  = (const float*)d_in[2];
  const float* Wk  = (const float*)d_in[3];
  const float* Wv  = (const float*)d_in[4];
  const float* Wo  = (const float*)d_in[5];
  const float* bo  = (const float*)d_in[6];
  const int*   ts  = (const int*)d_in[7];
  float* out = (float*)d_out;

  char* ws = (char*)d_ws;
  float*  Kws = (float*)(ws + K_OFF);
  float*  Vws = (float*)(ws + V_OFF);
  ushort* Aws = (ushort*)(ws + A_OFF);
  ushort* Cws = (ushort*)(ws + C_OFF);

  // zero A/C (padding rows/cols must be 0)
  hipMemsetAsync(ws + A_OFF, 0, 3276800, stream);

  kv_proj<<<160, 512, 0, stream>>>(ehs, Wk, Wv, ts, Kws, Vws);
  build_A<<<320, 256, 0, stream>>>(Kws, Wq, Aws);
  build_C<<<320, 256, 0, stream>>>(Vws, Wo, Cws);
  attn_main<<<1024, 256, 0, stream>>>(hs, Aws, Cws, bo, out);
}

// Round 2
// 488.245 us; speedup vs baseline: 1.5662x; 1.5662x over previous
//
#include <hip/hip_runtime.h>

// out = softmax_heads(hs @ A_b) @ C_b + bo + hs, with
//   A_b[320 x 640] = scale * Wq . K_b^T   (cols grouped: panel p(2) x head-in-panel(4) x 80, j>=77 zero)
//   C_b[640 x 320] = V_b . Wo             (rows grouped same way)
// A/C stored in MFMA fragment order: [b][p][w][nt5][ks10][lane64][e8] bf16 (1KB per frag, coalesced).

typedef __attribute__((ext_vector_type(8))) short short8_t;
typedef __attribute__((ext_vector_type(4))) float f32x4;

#define SQ     16384
#define CDIM   320
#define CXDIM  768
#define SKV    77

// ws layout (bytes)
#define K_OFF 0
#define V_OFF 394240
#define A_OFF 788480
#define C_OFF 2426880
// total 4065280

__device__ __forceinline__ ushort f2bf(float f) {
  union { float f; unsigned u; } x; x.f = f;
  unsigned u = x.u;
  return (ushort)((u + 0x7FFFu + ((u >> 16) & 1u)) >> 16);   // RNE
}
__device__ __forceinline__ float bf2f(ushort h) {
  union { unsigned u; float f; } x; x.u = ((unsigned)h) << 16;
  return x.f;
}

// swizzled byte address inside a [64][320]-ushort LDS tile (stride 640B, XOR bank swizzle)
#define SWZ(row, cb) ((((row) * 640 + (cb)) ^ (((row) & 7) << 4)))

// ---------------- P1: K/V = ehs @ {Wk,Wv}  (+ amplification on V) ----------------
// grid 160 = kv(2) x b(4) x rowgrp(20 of 4 rows), 320 threads (thread = output col)
__global__ __launch_bounds__(320) void kv_proj(
    const float* __restrict__ ehs, const float* __restrict__ Wk,
    const float* __restrict__ Wv, const int* __restrict__ tstep,
    float* __restrict__ Kws, float* __restrict__ Vws)
{
  int bx = blockIdx.x;
  int grp = bx % 20;
  int b   = (bx / 20) % 4;
  int kv  = bx / 80;
  const float* W = kv ? Wv : Wk;
  float* O = kv ? Vws : Kws;
  int t = threadIdx.x;

  __shared__ float er[4][CXDIM];
  const float* esrc = ehs + ((size_t)(b * SKV + grp * 4)) * CXDIM;
  for (int i = t; i < 4 * CXDIM; i += 320) {
    int r = i / CXDIM, d = i % CXDIM;
    er[r][d] = (grp * 4 + r < SKV) ? esrc[(size_t)r * CXDIM + d] : 0.f;
  }
  __syncthreads();

  float a0 = 0.f, a1 = 0.f, a2 = 0.f, a3 = 0.f;
  #pragma unroll 8
  for (int d = 0; d < CXDIM; ++d) {
    float wv = W[(size_t)d * CDIM + t];
    a0 += er[0][d] * wv;
    a1 += er[1][d] * wv;
    a2 += er[2][d] * wv;
    a3 += er[3][d] * wv;
  }
  float amp = fmaxf(1.0f, (float)(tstep[0] - 1) * 0.02f);
  float accs[4] = {a0, a1, a2, a3};
  #pragma unroll
  for (int r = 0; r < 4; ++r) {
    int s = grp * 4 + r;
    if (s < SKV) {
      float v = accs[r];
      if (kv && (b & 1) && (s == 2 || s == 5)) v *= amp;
      O[((size_t)(b * SKV + s)) * CDIM + t] = v;
    }
  }
}

// ---------------- P2: A fragments ----------------
// grid 32 = ((b*2+p)*4+w), 320 threads (thread = k in [0,320))
__global__ __launch_bounds__(320) void build_A(
    const float* __restrict__ Kws, const float* __restrict__ Wq,
    ushort* __restrict__ Afr)
{
  int bx = blockIdx.x;
  int w = bx & 3, p = (bx >> 2) & 1, b = bx >> 3;
  int h = p * 4 + w;
  int t = threadIdx.x;

  __shared__ float Kl[80][40];
  for (int i = t; i < 80 * 40; i += 320) {
    int j = i / 40, d = i % 40;
    Kl[j][d] = (j < SKV) ? Kws[((size_t)(b * SKV + j)) * CDIM + h * 40 + d] : 0.f;
  }
  __syncthreads();

  float wq[40];
  #pragma unroll
  for (int d = 0; d < 40; ++d)
    wq[d] = Wq[(size_t)t * CDIM + h * 40 + d] * 0.15811388f;   // 1/sqrt(40)

  int ks = t >> 5, l4 = (t >> 3) & 3, e = t & 7;
  ushort* dst = Afr + (size_t)bx * 25600;
  for (int j = 0; j < 80; ++j) {
    float a = 0.f, a2 = 0.f;
    #pragma unroll
    for (int d4 = 0; d4 < 10; ++d4) {
      float4 kv4 = *(const float4*)&Kl[j][d4 * 4];
      a  += wq[d4 * 4 + 0] * kv4.x + wq[d4 * 4 + 1] * kv4.y;
      a2 += wq[d4 * 4 + 2] * kv4.z + wq[d4 * 4 + 3] * kv4.w;
    }
    int nt = j >> 4, jl = j & 15;
    dst[(size_t)(((nt * 10 + ks) * 64 + l4 * 16 + jl) * 8 + e)] = f2bf(a + a2);
  }
}

// ---------------- P3: C fragments ----------------
// grid 32 = ((b*2+p)*4+w), 320 threads (thread = (hp = t/80, n_local = t%80))
__global__ __launch_bounds__(320) void build_C(
    const float* __restrict__ Vws, const float* __restrict__ Wo,
    ushort* __restrict__ Cfr)
{
  int bx = blockIdx.x;
  int w = bx & 3, p = (bx >> 2) & 1, b = bx >> 3;
  int t = threadIdx.x;

  __shared__ float Vl[80][160];
  for (int i = t; i < 80 * 160; i += 320) {
    int j = i / 160, dc = i % 160;
    Vl[j][dc] = (j < SKV) ? Vws[((size_t)(b * SKV + j)) * CDIM + p * 160 + dc] : 0.f;
  }
  __syncthreads();

  int nl = t % 80, hp = t / 80;
  int h = p * 4 + hp;
  int n = w * 80 + nl;
  float wo[40];
  #pragma unroll
  for (int d = 0; d < 40; ++d)
    wo[d] = Wo[((size_t)(h * 40 + d)) * CDIM + n];

  int nt = nl >> 4, jl = nl & 15;
  ushort* dst = Cfr + (size_t)bx * 25600;
  for (int j = 0; j < 80; ++j) {
    float a = 0.f, a2 = 0.f;
    #pragma unroll
    for (int d4 = 0; d4 < 10; ++d4) {
      float4 vv = *(const float4*)&Vl[j][hp * 40 + d4 * 4];
      a  += wo[d4 * 4 + 0] * vv.x + wo[d4 * 4 + 1] * vv.y;
      a2 += wo[d4 * 4 + 2] * vv.z + wo[d4 * 4 + 3] * vv.w;
    }
    int K = hp * 80 + j;
    int ks = K >> 5, l4 = (K >> 3) & 3, e = K & 7;
    dst[(size_t)(((nt * 10 + ks) * 64 + l4 * 16 + jl) * 8 + e)] = f2bf(a + a2);
  }
}

// ---------------- Main fused kernel ----------------
// grid 1024 = b(4) x rowtile(256 of 64 rows), 256 threads (4 waves; wave w owns 80-col slice, all 64 rows)
__global__ __launch_bounds__(256, 2) void attn_main(
    const float* __restrict__ hs, const ushort* __restrict__ Afr,
    const ushort* __restrict__ Cfr, const float* __restrict__ bo,
    float* __restrict__ out)
{
  __shared__ ushort lds_hs[64 * 320];
  __shared__ ushort lds_sp[64 * 320];

  int bx = blockIdx.x;
  int b = bx >> 8;
  int row0 = (bx & 255) << 6;
  int t = threadIdx.x;
  int w = t >> 6;
  int lane = t & 63;
  int l15 = lane & 15, l4 = lane >> 4;

  // ---- stage hs tile (f32 -> bf16, swizzled) ----
  const float* hsrc = hs + ((size_t)(b * SQ + row0)) * CDIM;
  #pragma unroll
  for (int it = 0; it < 20; ++it) {
    int s = t + 256 * it;              // float4 index, 5120 total (80 per row)
    int r = s / 80, f = s % 80;
    float4 v = ((const float4*)hsrc)[s];
    ushort4 u;
    u.x = f2bf(v.x); u.y = f2bf(v.y); u.z = f2bf(v.z); u.w = f2bf(v.w);
    *(ushort4*)((char*)lds_hs + SWZ(r, f * 8)) = u;
  }
  __syncthreads();

  f32x4 acc2[4][5];
  #pragma unroll
  for (int m = 0; m < 4; ++m)
    #pragma unroll
    for (int nt = 0; nt < 5; ++nt) acc2[m][nt] = (f32x4){0.f, 0.f, 0.f, 0.f};

  for (int p = 0; p < 2; ++p) {
    // ---- GEMM1: S[64][w*80..+80] = hs_tile @ A_panel_slice ----
    const ushort* Ap = Afr + (size_t)(((b * 2 + p) * 4 + w)) * 25600 + (size_t)lane * 8;
    f32x4 acc1[4][5];
    #pragma unroll
    for (int m = 0; m < 4; ++m)
      #pragma unroll
      for (int nt = 0; nt < 5; ++nt) acc1[m][nt] = (f32x4){0.f, 0.f, 0.f, 0.f};

    #pragma unroll
    for (int ks = 0; ks < 10; ++ks) {
      short8_t af[5];
      #pragma unroll
      for (int nt = 0; nt < 5; ++nt)
        af[nt] = *(const short8_t*)(Ap + (size_t)(nt * 10 + ks) * 512);
      short8_t hf[4];
      #pragma unroll
      for (int m = 0; m < 4; ++m)
        hf[m] = *(const short8_t*)((char*)lds_hs + SWZ(m * 16 + l15, ks * 64 + l4 * 16));
      #pragma unroll
      for (int m = 0; m < 4; ++m)
        #pragma unroll
        for (int nt = 0; nt < 5; ++nt)
          acc1[m][nt] = __builtin_amdgcn_mfma_f32_16x16x32_bf16(hf[m], af[nt], acc1[m][nt], 0, 0, 0);
    }
    // write S (bf16, swizzled)
    #pragma unroll
    for (int m = 0; m < 4; ++m)
      #pragma unroll
      for (int nt = 0; nt < 5; ++nt)
        #pragma unroll
        for (int r = 0; r < 4; ++r)
          *(ushort*)((char*)lds_sp + SWZ(m * 16 + l4 * 4 + r, (w * 80 + nt * 16 + l15) * 2)) =
              f2bf(acc1[m][nt][r]);
    __syncthreads();

    // ---- softmax: thread -> (row = t&63, head hp = t>>6), 80 cols, pads masked ----
    {
      int row = t & 63, hp = t >> 6;
      float ef[80];
      #pragma unroll
      for (int q = 0; q < 10; ++q) {
        short8_t c = *(const short8_t*)((char*)lds_sp + SWZ(row, hp * 160 + q * 16));
        #pragma unroll
        for (int e = 0; e < 8; ++e) ef[q * 8 + e] = bf2f((ushort)c[e]);
      }
      float mx = -1e30f;
      #pragma unroll
      for (int j = 0; j < 77; ++j) mx = fmaxf(mx, ef[j]);
      float sum = 0.f;
      #pragma unroll
      for (int j = 0; j < 80; ++j) {
        float ev = (j < 77) ? __expf(ef[j] - mx) : 0.f;
        ef[j] = ev;
        sum += ev;
      }
      float inv = 1.0f / sum;
      #pragma unroll
      for (int q = 0; q < 10; ++q) {
        short8_t o;
        #pragma unroll
        for (int e = 0; e < 8; ++e) o[e] = (short)f2bf(ef[q * 8 + e] * inv);
        *(short8_t*)((char*)lds_sp + SWZ(row, hp * 160 + q * 16)) = o;
      }
    }
    __syncthreads();

    // ---- GEMM2: out_slice[64][w*80..+80] += P_panel @ C_panel_slice ----
    const ushort* Cp = Cfr + (size_t)(((b * 2 + p) * 4 + w)) * 25600 + (size_t)lane * 8;
    #pragma unroll
    for (int ks = 0; ks < 10; ++ks) {
      short8_t cf[5];
      #pragma unroll
      for (int nt = 0; nt < 5; ++nt)
        cf[nt] = *(const short8_t*)(Cp + (size_t)(nt * 10 + ks) * 512);
      short8_t pf[4];
      #pragma unroll
      for (int m = 0; m < 4; ++m)
        pf[m] = *(const short8_t*)((char*)lds_sp + SWZ(m * 16 + l15, ks * 64 + l4 * 16));
      #pragma unroll
      for (int m = 0; m < 4; ++m)
        #pragma unroll
        for (int nt = 0; nt < 5; ++nt)
          acc2[m][nt] = __builtin_amdgcn_mfma_f32_16x16x32_bf16(pf[m], cf[nt], acc2[m][nt], 0, 0, 0);
    }
    __syncthreads();   // protect lds_sp before next panel's S-write
  }

  // ---- epilogue: + bo + residual(f32), store ----
  #pragma unroll
  for (int m = 0; m < 4; ++m) {
    #pragma unroll
    for (int nt = 0; nt < 5; ++nt) {
      int col = w * 80 + nt * 16 + l15;
      float bov = bo[col];
      #pragma unroll
      for (int r = 0; r < 4; ++r) {
        int rowg = row0 + m * 16 + l4 * 4 + r;
        size_t oi = ((size_t)(b * SQ + rowg)) * CDIM + col;
        out[oi] = acc2[m][nt][r] + bov + hs[oi];
      }
    }
  }
}

extern "C" void kernel_launch(void* const* d_in, const int* in_sizes, int n_in,
                              void* d_out, int out_size, void* d_ws, size_t ws_size,
                              hipStream_t stream) {
  const float* hs  = (const float*)d_in[0];
  const float* ehs = (const float*)d_in[1];
  const float* Wq  = (const float*)d_in[2];
  const float* Wk  = (const float*)d_in[3];
  const float* Wv  = (const float*)d_in[4];
  const float* Wo  = (const float*)d_in[5];
  const float* bo  = (const float*)d_in[6];
  const int*   ts  = (const int*)d_in[7];
  float* out = (float*)d_out;

  char* ws = (char*)d_ws;
  float*  Kws = (float*)(ws + K_OFF);
  float*  Vws = (float*)(ws + V_OFF);
  ushort* Afr = (ushort*)(ws + A_OFF);
  ushort* Cfr = (ushort*)(ws + C_OFF);

  kv_proj<<<160, 320, 0, stream>>>(ehs, Wk, Wv, ts, Kws, Vws);
  build_A<<<32, 320, 0, stream>>>(Kws, Wq, Afr);
  build_C<<<32, 320, 0, stream>>>(Vws, Wo, Cfr);
  attn_main<<<1024, 256, 0, stream>>>(hs, Afr, Cfr, bo, out);
}

// Round 3
// 485.948 us; speedup vs baseline: 1.5736x; 1.0047x over previous
//
#include <hip/hip_runtime.h>

// out = softmax_heads(hs @ A_b) @ C_b + bo + hs, with
//   A_b[320 x 640] = scale * Wq . K_b^T   (cols grouped: panel p(2) x head-in-panel(4) x 80, j>=77 zero)
//   C_b[640 x 320] = V_b . Wo             (rows grouped same way)
// A/C stored in MFMA fragment order: [b][p][w][nt5][ks10][lane64][e8] bf16 (1KB per frag, coalesced).
// Softmax is done fully in registers on the GEMM1 accumulator (no LDS round-trip, no spills).

typedef __attribute__((ext_vector_type(8))) short short8_t;
typedef __attribute__((ext_vector_type(4))) float f32x4;

#define SQ     16384
#define CDIM   320
#define CXDIM  768
#define SKV    77

// ws layout (bytes)
#define K_OFF 0
#define V_OFF 394240
#define A_OFF 788480
#define C_OFF 2426880
// total 4065280

__device__ __forceinline__ ushort f2bf(float f) {
  union { float f; unsigned u; } x; x.f = f;
  unsigned u = x.u;
  return (ushort)((u + 0x7FFFu + ((u >> 16) & 1u)) >> 16);   // RNE
}
__device__ __forceinline__ float bf2f(ushort h) {
  union { unsigned u; float f; } x; x.u = ((unsigned)h) << 16;
  return x.f;
}

// swizzled byte address inside a [64][320]-ushort LDS tile (stride 640B, XOR bank swizzle)
#define SWZ(row, cb) ((((row) * 640 + (cb)) ^ (((row) & 7) << 4)))

// ---------------- P1: K/V = ehs @ {Wk,Wv}  (+ amplification on V) ----------------
// grid 160 = kv(2) x b(4) x rowgrp(20 of 4 rows), 320 threads (thread = output col)
__global__ __launch_bounds__(320) void kv_proj(
    const float* __restrict__ ehs, const float* __restrict__ Wk,
    const float* __restrict__ Wv, const int* __restrict__ tstep,
    float* __restrict__ Kws, float* __restrict__ Vws)
{
  int bx = blockIdx.x;
  int grp = bx % 20;
  int b   = (bx / 20) % 4;
  int kv  = bx / 80;
  const float* W = kv ? Wv : Wk;
  float* O = kv ? Vws : Kws;
  int t = threadIdx.x;

  __shared__ float er[4][CXDIM];
  const float* esrc = ehs + ((size_t)(b * SKV + grp * 4)) * CXDIM;
  for (int i = t; i < 4 * CXDIM; i += 320) {
    int r = i / CXDIM, d = i % CXDIM;
    er[r][d] = (grp * 4 + r < SKV) ? esrc[(size_t)r * CXDIM + d] : 0.f;
  }
  __syncthreads();

  float a0 = 0.f, a1 = 0.f, a2 = 0.f, a3 = 0.f;
  #pragma unroll 8
  for (int d = 0; d < CXDIM; ++d) {
    float wv = W[(size_t)d * CDIM + t];
    a0 += er[0][d] * wv;
    a1 += er[1][d] * wv;
    a2 += er[2][d] * wv;
    a3 += er[3][d] * wv;
  }
  float amp = fmaxf(1.0f, (float)(tstep[0] - 1) * 0.02f);
  float accs[4] = {a0, a1, a2, a3};
  #pragma unroll
  for (int r = 0; r < 4; ++r) {
    int s = grp * 4 + r;
    if (s < SKV) {
      float v = accs[r];
      if (kv && (b & 1) && (s == 2 || s == 5)) v *= amp;
      O[((size_t)(b * SKV + s)) * CDIM + t] = v;
    }
  }
}

// ---------------- P2: A fragments ----------------
// grid 32 = ((b*2+p)*4+w), 320 threads (thread = k in [0,320))
__global__ __launch_bounds__(320) void build_A(
    const float* __restrict__ Kws, const float* __restrict__ Wq,
    ushort* __restrict__ Afr)
{
  int bx = blockIdx.x;
  int w = bx & 3, p = (bx >> 2) & 1, b = bx >> 3;
  int h = p * 4 + w;
  int t = threadIdx.x;

  __shared__ float Kl[80][40];
  for (int i = t; i < 80 * 40; i += 320) {
    int j = i / 40, d = i % 40;
    Kl[j][d] = (j < SKV) ? Kws[((size_t)(b * SKV + j)) * CDIM + h * 40 + d] : 0.f;
  }
  __syncthreads();

  float wq[40];
  #pragma unroll
  for (int d = 0; d < 40; ++d)
    wq[d] = Wq[(size_t)t * CDIM + h * 40 + d] * 0.15811388f;   // 1/sqrt(40)

  int ks = t >> 5, l4 = (t >> 3) & 3, e = t & 7;
  ushort* dst = Afr + (size_t)bx * 25600;
  for (int j = 0; j < 80; ++j) {
    float a = 0.f, a2 = 0.f;
    #pragma unroll
    for (int d4 = 0; d4 < 10; ++d4) {
      float4 kv4 = *(const float4*)&Kl[j][d4 * 4];
      a  += wq[d4 * 4 + 0] * kv4.x + wq[d4 * 4 + 1] * kv4.y;
      a2 += wq[d4 * 4 + 2] * kv4.z + wq[d4 * 4 + 3] * kv4.w;
    }
    int nt = j >> 4, jl = j & 15;
    dst[(size_t)(((nt * 10 + ks) * 64 + l4 * 16 + jl) * 8 + e)] = f2bf(a + a2);
  }
}

// ---------------- P3: C fragments ----------------
// grid 32 = ((b*2+p)*4+w), 320 threads (thread = (hp = t/80, n_local = t%80))
__global__ __launch_bounds__(320) void build_C(
    const float* __restrict__ Vws, const float* __restrict__ Wo,
    ushort* __restrict__ Cfr)
{
  int bx = blockIdx.x;
  int w = bx & 3, p = (bx >> 2) & 1, b = bx >> 3;
  int t = threadIdx.x;

  __shared__ float Vl[80][160];
  for (int i = t; i < 80 * 160; i += 320) {
    int j = i / 160, dc = i % 160;
    Vl[j][dc] = (j < SKV) ? Vws[((size_t)(b * SKV + j)) * CDIM + p * 160 + dc] : 0.f;
  }
  __syncthreads();

  int nl = t % 80, hp = t / 80;
  int h = p * 4 + hp;
  int n = w * 80 + nl;
  float wo[40];
  #pragma unroll
  for (int d = 0; d < 40; ++d)
    wo[d] = Wo[((size_t)(h * 40 + d)) * CDIM + n];

  int nt = nl >> 4, jl = nl & 15;
  ushort* dst = Cfr + (size_t)bx * 25600;
  for (int j = 0; j < 80; ++j) {
    float a = 0.f, a2 = 0.f;
    #pragma unroll
    for (int d4 = 0; d4 < 10; ++d4) {
      float4 vv = *(const float4*)&Vl[j][hp * 40 + d4 * 4];
      a  += wo[d4 * 4 + 0] * vv.x + wo[d4 * 4 + 1] * vv.y;
      a2 += wo[d4 * 4 + 2] * vv.z + wo[d4 * 4 + 3] * vv.w;
    }
    int K = hp * 80 + j;
    int ks = K >> 5, l4 = (K >> 3) & 3, e = K & 7;
    dst[(size_t)(((nt * 10 + ks) * 64 + l4 * 16 + jl) * 8 + e)] = f2bf(a + a2);
  }
}

// ---------------- Main fused kernel ----------------
// grid 1024 = b(4) x rowtile(256 of 64 rows), 256 threads (4 waves; wave w owns 80-col slice = head p*4+w)
__global__ __launch_bounds__(256, 2) void attn_main(
    const float* __restrict__ hs, const ushort* __restrict__ Afr,
    const ushort* __restrict__ Cfr, const float* __restrict__ bo,
    float* __restrict__ out)
{
  __shared__ ushort lds_hs[64 * 320];
  __shared__ ushort lds_sp[64 * 320];

  int bx = blockIdx.x;
  int b = bx >> 8;
  int row0 = (bx & 255) << 6;
  int t = threadIdx.x;
  int w = t >> 6;
  int lane = t & 63;
  int l15 = lane & 15, l4 = lane >> 4;

  // ---- stage hs tile (f32 -> bf16, swizzled) ----
  const float* hsrc = hs + ((size_t)(b * SQ + row0)) * CDIM;
  #pragma unroll
  for (int it = 0; it < 20; ++it) {
    int s = t + 256 * it;              // float4 index, 5120 total (80 per row)
    int r = s / 80, f = s % 80;
    float4 v = ((const float4*)hsrc)[s];
    ushort4 u;
    u.x = f2bf(v.x); u.y = f2bf(v.y); u.z = f2bf(v.z); u.w = f2bf(v.w);
    *(ushort4*)((char*)lds_hs + SWZ(r, f * 8)) = u;
  }
  __syncthreads();

  f32x4 acc2[4][5];
  #pragma unroll
  for (int m = 0; m < 4; ++m)
    #pragma unroll
    for (int nt = 0; nt < 5; ++nt) acc2[m][nt] = (f32x4){0.f, 0.f, 0.f, 0.f};

  for (int p = 0; p < 2; ++p) {
    // ---- GEMM1: S[64][w*80..+80] = hs_tile @ A_panel_slice ----
    const ushort* Ap = Afr + (size_t)(((b * 2 + p) * 4 + w)) * 25600 + (size_t)lane * 8;
    f32x4 acc1[4][5];
    #pragma unroll
    for (int m = 0; m < 4; ++m)
      #pragma unroll
      for (int nt = 0; nt < 5; ++nt) acc1[m][nt] = (f32x4){0.f, 0.f, 0.f, 0.f};

    #pragma unroll
    for (int ks = 0; ks < 10; ++ks) {
      short8_t af[5];
      #pragma unroll
      for (int nt = 0; nt < 5; ++nt)
        af[nt] = *(const short8_t*)(Ap + (size_t)(nt * 10 + ks) * 512);
      short8_t hf[4];
      #pragma unroll
      for (int m = 0; m < 4; ++m)
        hf[m] = *(const short8_t*)((char*)lds_hs + SWZ(m * 16 + l15, ks * 64 + l4 * 16));
      #pragma unroll
      for (int m = 0; m < 4; ++m)
        #pragma unroll
        for (int nt = 0; nt < 5; ++nt)
          acc1[m][nt] = __builtin_amdgcn_mfma_f32_16x16x32_bf16(hf[m], af[nt], acc1[m][nt], 0, 0, 0);
    }

    // ---- softmax fully in registers on acc1 ----
    // thread holds S[m*16+l4*4+r][w*80 + nt*16 + l15]; row-reduce = 5 regs + shfl_xor over l15.
    // pad cols (nt==4, l15>=13) excluded from max/sum; their P is 0 (and C rows >=77 are 0 anyway).
    bool pad = (l15 >= 13);
    #pragma unroll
    for (int m = 0; m < 4; ++m) {
      #pragma unroll
      for (int r = 0; r < 4; ++r) {
        float v0 = acc1[m][0][r], v1 = acc1[m][1][r];
        float v2 = acc1[m][2][r], v3 = acc1[m][3][r];
        float v4 = pad ? -1e30f : acc1[m][4][r];
        float mx = fmaxf(fmaxf(fmaxf(v0, v1), fmaxf(v2, v3)), v4);
        mx = fmaxf(mx, __shfl_xor(mx, 1));
        mx = fmaxf(mx, __shfl_xor(mx, 2));
        mx = fmaxf(mx, __shfl_xor(mx, 4));
        mx = fmaxf(mx, __shfl_xor(mx, 8));
        float e0 = __expf(v0 - mx), e1 = __expf(v1 - mx);
        float e2 = __expf(v2 - mx), e3 = __expf(v3 - mx);
        float e4 = pad ? 0.f : __expf(v4 - mx);
        float sum = (e0 + e1) + (e2 + e3) + e4;
        sum += __shfl_xor(sum, 1);
        sum += __shfl_xor(sum, 2);
        sum += __shfl_xor(sum, 4);
        sum += __shfl_xor(sum, 8);
        float inv = __builtin_amdgcn_rcpf(sum);
        acc1[m][0][r] = e0 * inv;
        acc1[m][1][r] = e1 * inv;
        acc1[m][2][r] = e2 * inv;
        acc1[m][3][r] = e3 * inv;
        acc1[m][4][r] = e4 * inv;
      }
    }

    // ---- write P (bf16, swizzled) ----
    #pragma unroll
    for (int m = 0; m < 4; ++m)
      #pragma unroll
      for (int nt = 0; nt < 5; ++nt)
        #pragma unroll
        for (int r = 0; r < 4; ++r)
          *(ushort*)((char*)lds_sp + SWZ(m * 16 + l4 * 4 + r, (w * 80 + nt * 16 + l15) * 2)) =
              f2bf(acc1[m][nt][r]);
    __syncthreads();

    // ---- GEMM2: out_slice[64][w*80..+80] += P_panel @ C_panel_slice ----
    const ushort* Cp = Cfr + (size_t)(((b * 2 + p) * 4 + w)) * 25600 + (size_t)lane * 8;
    #pragma unroll
    for (int ks = 0; ks < 10; ++ks) {
      short8_t cf[5];
      #pragma unroll
      for (int nt = 0; nt < 5; ++nt)
        cf[nt] = *(const short8_t*)(Cp + (size_t)(nt * 10 + ks) * 512);
      short8_t pf[4];
      #pragma unroll
      for (int m = 0; m < 4; ++m)
        pf[m] = *(const short8_t*)((char*)lds_sp + SWZ(m * 16 + l15, ks * 64 + l4 * 16));
      #pragma unroll
      for (int m = 0; m < 4; ++m)
        #pragma unroll
        for (int nt = 0; nt < 5; ++nt)
          acc2[m][nt] = __builtin_amdgcn_mfma_f32_16x16x32_bf16(pf[m], cf[nt], acc2[m][nt], 0, 0, 0);
    }
    if (p == 0) __syncthreads();   // protect lds_sp before next panel's P-write
  }

  // ---- epilogue: + bo + residual(f32), store ----
  #pragma unroll
  for (int m = 0; m < 4; ++m) {
    #pragma unroll
    for (int nt = 0; nt < 5; ++nt) {
      int col = w * 80 + nt * 16 + l15;
      float bov = bo[col];
      #pragma unroll
      for (int r = 0; r < 4; ++r) {
        int rowg = row0 + m * 16 + l4 * 4 + r;
        size_t oi = ((size_t)(b * SQ + rowg)) * CDIM + col;
        out[oi] = acc2[m][nt][r] + bov + hs[oi];
      }
    }
  }
}

extern "C" void kernel_launch(void* const* d_in, const int* in_sizes, int n_in,
                              void* d_out, int out_size, void* d_ws, size_t ws_size,
                              hipStream_t stream) {
  const float* hs  = (const float*)d_in[0];
  const float* ehs = (const float*)d_in[1];
  const float* Wq  = (const float*)d_in[2];
  const float* Wk  = (const float*)d_in[3];
  const float* Wv  = (const float*)d_in[4];
  const float* Wo  = (const float*)d_in[5];
  const float* bo  = (const float*)d_in[6];
  const int*   ts  = (const int*)d_in[7];
  float* out = (float*)d_out;

  char* ws = (char*)d_ws;
  float*  Kws = (float*)(ws + K_OFF);
  float*  Vws = (float*)(ws + V_OFF);
  ushort* Afr = (ushort*)(ws + A_OFF);
  ushort* Cfr = (ushort*)(ws + C_OFF);

  kv_proj<<<160, 320, 0, stream>>>(ehs, Wk, Wv, ts, Kws, Vws);
  build_A<<<32, 320, 0, stream>>>(Kws, Wq, Afr);
  build_C<<<32, 320, 0, stream>>>(Vws, Wo, Cfr);
  attn_main<<<1024, 256, 0, stream>>>(hs, Afr, Cfr, bo, out);
}

// Round 4
// 365.845 us; speedup vs baseline: 2.0903x; 1.3283x over previous
//
#include <hip/hip_runtime.h>

// out = softmax_heads(hs @ A_b) @ C_b + bo + hs, with
//   A_b[320 x 640] = scale * Wq . K_b^T   (cols grouped: panel p(2) x head-in-panel(4) x 80, j>=77 zero)
//   C_b[640 x 320] = V_b . Wo             (rows grouped same way)
// A/C stored in MFMA fragment order: [b][p][w][nt5][ks10][lane64][e8] bf16 (1KB per frag, coalesced).
// Softmax fully in registers on the GEMM1 accumulator.
// Spill-free phase structure: GEMM1(p0)->P0 LDS; GEMM1(p1) reuses acc1; P1 overwrites hs tile;
// then GEMM2 over both panels with only acc2 live. Peak ~130 VGPRs.

typedef __attribute__((ext_vector_type(8))) short short8_t;
typedef __attribute__((ext_vector_type(4))) float f32x4;

#define SQ     16384
#define CDIM   320
#define CXDIM  768
#define SKV    77

// ws layout (bytes)
#define K_OFF 0
#define V_OFF 394240
#define A_OFF 788480
#define C_OFF 2426880
// total 4065280

__device__ __forceinline__ ushort f2bf(float f) {
  union { float f; unsigned u; } x; x.f = f;
  unsigned u = x.u;
  return (ushort)((u + 0x7FFFu + ((u >> 16) & 1u)) >> 16);   // RNE
}

// swizzled byte address inside a [64][320]-ushort LDS tile (stride 640B, XOR bank swizzle)
#define SWZ(row, cb) ((((row) * 640 + (cb)) ^ (((row) & 7) << 4)))

// ---------------- P1: K/V = ehs @ {Wk,Wv}  (+ amplification on V) ----------------
// grid 160 = kv(2) x b(4) x rowgrp(20 of 4 rows), 320 threads (thread = output col)
__global__ __launch_bounds__(320) void kv_proj(
    const float* __restrict__ ehs, const float* __restrict__ Wk,
    const float* __restrict__ Wv, const int* __restrict__ tstep,
    float* __restrict__ Kws, float* __restrict__ Vws)
{
  int bx = blockIdx.x;
  int grp = bx % 20;
  int b   = (bx / 20) % 4;
  int kv  = bx / 80;
  const float* W = kv ? Wv : Wk;
  float* O = kv ? Vws : Kws;
  int t = threadIdx.x;

  __shared__ float er[4][CXDIM];
  const float* esrc = ehs + ((size_t)(b * SKV + grp * 4)) * CXDIM;
  for (int i = t; i < 4 * CXDIM; i += 320) {
    int r = i / CXDIM, d = i % CXDIM;
    er[r][d] = (grp * 4 + r < SKV) ? esrc[(size_t)r * CXDIM + d] : 0.f;
  }
  __syncthreads();

  float a0 = 0.f, a1 = 0.f, a2 = 0.f, a3 = 0.f;
  #pragma unroll 8
  for (int d = 0; d < CXDIM; ++d) {
    float wv = W[(size_t)d * CDIM + t];
    a0 += er[0][d] * wv;
    a1 += er[1][d] * wv;
    a2 += er[2][d] * wv;
    a3 += er[3][d] * wv;
  }
  float amp = fmaxf(1.0f, (float)(tstep[0] - 1) * 0.02f);
  float accs[4] = {a0, a1, a2, a3};
  #pragma unroll
  for (int r = 0; r < 4; ++r) {
    int s = grp * 4 + r;
    if (s < SKV) {
      float v = accs[r];
      if (kv && (b & 1) && (s == 2 || s == 5)) v *= amp;
      O[((size_t)(b * SKV + s)) * CDIM + t] = v;
    }
  }
}

// ---------------- P2: A fragments ----------------
// grid 32 = ((b*2+p)*4+w), 320 threads (thread = k in [0,320))
__global__ __launch_bounds__(320) void build_A(
    const float* __restrict__ Kws, const float* __restrict__ Wq,
    ushort* __restrict__ Afr)
{
  int bx = blockIdx.x;
  int w = bx & 3, p = (bx >> 2) & 1, b = bx >> 3;
  int h = p * 4 + w;
  int t = threadIdx.x;

  __shared__ float Kl[80][40];
  for (int i = t; i < 80 * 40; i += 320) {
    int j = i / 40, d = i % 40;
    Kl[j][d] = (j < SKV) ? Kws[((size_t)(b * SKV + j)) * CDIM + h * 40 + d] : 0.f;
  }
  __syncthreads();

  float wq[40];
  #pragma unroll
  for (int d = 0; d < 40; ++d)
    wq[d] = Wq[(size_t)t * CDIM + h * 40 + d] * 0.15811388f;   // 1/sqrt(40)

  int ks = t >> 5, l4 = (t >> 3) & 3, e = t & 7;
  ushort* dst = Afr + (size_t)bx * 25600;
  for (int j = 0; j < 80; ++j) {
    float a = 0.f, a2 = 0.f;
    #pragma unroll
    for (int d4 = 0; d4 < 10; ++d4) {
      float4 kv4 = *(const float4*)&Kl[j][d4 * 4];
      a  += wq[d4 * 4 + 0] * kv4.x + wq[d4 * 4 + 1] * kv4.y;
      a2 += wq[d4 * 4 + 2] * kv4.z + wq[d4 * 4 + 3] * kv4.w;
    }
    int nt = j >> 4, jl = j & 15;
    dst[(size_t)(((nt * 10 + ks) * 64 + l4 * 16 + jl) * 8 + e)] = f2bf(a + a2);
  }
}

// ---------------- P3: C fragments ----------------
// grid 32 = ((b*2+p)*4+w), 320 threads (thread = (hp = t/80, n_local = t%80))
__global__ __launch_bounds__(320) void build_C(
    const float* __restrict__ Vws, const float* __restrict__ Wo,
    ushort* __restrict__ Cfr)
{
  int bx = blockIdx.x;
  int w = bx & 3, p = (bx >> 2) & 1, b = bx >> 3;
  int t = threadIdx.x;

  __shared__ float Vl[80][160];
  for (int i = t; i < 80 * 160; i += 320) {
    int j = i / 160, dc = i % 160;
    Vl[j][dc] = (j < SKV) ? Vws[((size_t)(b * SKV + j)) * CDIM + p * 160 + dc] : 0.f;
  }
  __syncthreads();

  int nl = t % 80, hp = t / 80;
  int h = p * 4 + hp;
  int n = w * 80 + nl;
  float wo[40];
  #pragma unroll
  for (int d = 0; d < 40; ++d)
    wo[d] = Wo[((size_t)(h * 40 + d)) * CDIM + n];

  int nt = nl >> 4, jl = nl & 15;
  ushort* dst = Cfr + (size_t)bx * 25600;
  for (int j = 0; j < 80; ++j) {
    float a = 0.f, a2 = 0.f;
    #pragma unroll
    for (int d4 = 0; d4 < 10; ++d4) {
      float4 vv = *(const float4*)&Vl[j][hp * 40 + d4 * 4];
      a  += wo[d4 * 4 + 0] * vv.x + wo[d4 * 4 + 1] * vv.y;
      a2 += wo[d4 * 4 + 2] * vv.z + wo[d4 * 4 + 3] * vv.w;
    }
    int K = hp * 80 + j;
    int ks = K >> 5, l4 = (K >> 3) & 3, e = K & 7;
    dst[(size_t)(((nt * 10 + ks) * 64 + l4 * 16 + jl) * 8 + e)] = f2bf(a + a2);
  }
}

// ---------------- Main fused kernel ----------------
// grid 1024 = b(4) x rowtile(256 of 64 rows), 256 threads (4 waves; wave w owns 80-col slice = head p*4+w)
__global__ __launch_bounds__(256, 2) void attn_main(
    const float* __restrict__ hs, const ushort* __restrict__ Afr,
    const ushort* __restrict__ Cfr, const float* __restrict__ bo,
    float* __restrict__ out)
{
  __shared__ ushort lds_hs[64 * 320];   // hs tile; later reused for P1
  __shared__ ushort lds_p0[64 * 320];   // P0

  int bxr = blockIdx.x;
  int bx = ((bxr & 7) << 7) | (bxr >> 3);    // bijective XCD swizzle (1024 % 8 == 0)
  int b = bx >> 8;
  int row0 = (bx & 255) << 6;
  int t = threadIdx.x;
  int w = t >> 6;
  int lane = t & 63;
  int l15 = lane & 15, l4 = lane >> 4;

  // ---- stage hs tile (f32 -> bf16, swizzled) ----
  const float* hsrc = hs + ((size_t)(b * SQ + row0)) * CDIM;
  #pragma unroll
  for (int it = 0; it < 20; ++it) {
    int s = t + 256 * it;              // float4 index, 5120 total (80 per row)
    int r = s / 80, f = s % 80;
    float4 v = ((const float4*)hsrc)[s];
    ushort4 u;
    u.x = f2bf(v.x); u.y = f2bf(v.y); u.z = f2bf(v.z); u.w = f2bf(v.w);
    *(ushort4*)((char*)lds_hs + SWZ(r, f * 8)) = u;
  }
  __syncthreads();

  const bool pad = (l15 >= 13);

  // ---- panels: GEMM1 + in-register softmax; P0 -> lds_p0, P1 -> lds_hs (reuse) ----
  #pragma unroll
  for (int p = 0; p < 2; ++p) {
    const ushort* Ap = Afr + (size_t)(((b * 2 + p) * 4 + w)) * 25600 + (size_t)lane * 8;
    f32x4 acc1[4][5];
    #pragma unroll
    for (int m = 0; m < 4; ++m)
      #pragma unroll
      for (int nt = 0; nt < 5; ++nt) acc1[m][nt] = (f32x4){0.f, 0.f, 0.f, 0.f};

    #pragma unroll
    for (int ks = 0; ks < 10; ++ks) {
      short8_t af[5];
      #pragma unroll
      for (int nt = 0; nt < 5; ++nt)
        af[nt] = *(const short8_t*)(Ap + (size_t)(nt * 10 + ks) * 512);
      short8_t hf[4];
      #pragma unroll
      for (int m = 0; m < 4; ++m)
        hf[m] = *(const short8_t*)((char*)lds_hs + SWZ(m * 16 + l15, ks * 64 + l4 * 16));
      #pragma unroll
      for (int m = 0; m < 4; ++m)
        #pragma unroll
        for (int nt = 0; nt < 5; ++nt)
          acc1[m][nt] = __builtin_amdgcn_mfma_f32_16x16x32_bf16(hf[m], af[nt], acc1[m][nt], 0, 0, 0);
    }

    // softmax in registers (row = m*16+l4*4+r; 80 cols = 5 regs x 16 l15-lanes)
    #pragma unroll
    for (int m = 0; m < 4; ++m) {
      #pragma unroll
      for (int r = 0; r < 4; ++r) {
        float v0 = acc1[m][0][r], v1 = acc1[m][1][r];
        float v2 = acc1[m][2][r], v3 = acc1[m][3][r];
        float v4 = pad ? -1e30f : acc1[m][4][r];
        float mx = fmaxf(fmaxf(fmaxf(v0, v1), fmaxf(v2, v3)), v4);
        mx = fmaxf(mx, __shfl_xor(mx, 1));
        mx = fmaxf(mx, __shfl_xor(mx, 2));
        mx = fmaxf(mx, __shfl_xor(mx, 4));
        mx = fmaxf(mx, __shfl_xor(mx, 8));
        float e0 = __expf(v0 - mx), e1 = __expf(v1 - mx);
        float e2 = __expf(v2 - mx), e3 = __expf(v3 - mx);
        float e4 = pad ? 0.f : __expf(v4 - mx);
        float sum = (e0 + e1) + (e2 + e3) + e4;
        sum += __shfl_xor(sum, 1);
        sum += __shfl_xor(sum, 2);
        sum += __shfl_xor(sum, 4);
        sum += __shfl_xor(sum, 8);
        float inv = __builtin_amdgcn_rcpf(sum);
        acc1[m][0][r] = e0 * inv;
        acc1[m][1][r] = e1 * inv;
        acc1[m][2][r] = e2 * inv;
        acc1[m][3][r] = e3 * inv;
        acc1[m][4][r] = e4 * inv;
      }
    }

    if (p == 1) __syncthreads();   // all waves done reading lds_hs before P1 overwrites it
    ushort* dstP = p ? lds_hs : lds_p0;
    #pragma unroll
    for (int m = 0; m < 4; ++m)
      #pragma unroll
      for (int nt = 0; nt < 5; ++nt)
        #pragma unroll
        for (int r = 0; r < 4; ++r)
          *(ushort*)((char*)dstP + SWZ(m * 16 + l4 * 4 + r, (w * 80 + nt * 16 + l15) * 2)) =
              f2bf(acc1[m][nt][r]);
  }
  __syncthreads();   // P0 + P1 visible

  // ---- GEMM2: acc2 = P0 @ C0 + P1 @ C1 (only acc2 live) ----
  f32x4 acc2[4][5];
  #pragma unroll
  for (int m = 0; m < 4; ++m)
    #pragma unroll
    for (int nt = 0; nt < 5; ++nt) acc2[m][nt] = (f32x4){0.f, 0.f, 0.f, 0.f};

  #pragma unroll
  for (int p = 0; p < 2; ++p) {
    const ushort* Cp = Cfr + (size_t)(((b * 2 + p) * 4 + w)) * 25600 + (size_t)lane * 8;
    const ushort* Psrc = p ? lds_hs : lds_p0;
    #pragma unroll
    for (int ks = 0; ks < 10; ++ks) {
      short8_t cf[5];
      #pragma unroll
      for (int nt = 0; nt < 5; ++nt)
        cf[nt] = *(const short8_t*)(Cp + (size_t)(nt * 10 + ks) * 512);
      short8_t pf[4];
      #pragma unroll
      for (int m = 0; m < 4; ++m)
        pf[m] = *(const short8_t*)((char*)Psrc + SWZ(m * 16 + l15, ks * 64 + l4 * 16));
      #pragma unroll
      for (int m = 0; m < 4; ++m)
        #pragma unroll
        for (int nt = 0; nt < 5; ++nt)
          acc2[m][nt] = __builtin_amdgcn_mfma_f32_16x16x32_bf16(pf[m], cf[nt], acc2[m][nt], 0, 0, 0);
    }
  }

  // ---- epilogue: + bo + residual(f32), store ----
  #pragma unroll
  for (int m = 0; m < 4; ++m) {
    #pragma unroll
    for (int nt = 0; nt < 5; ++nt) {
      int col = w * 80 + nt * 16 + l15;
      float bov = bo[col];
      #pragma unroll
      for (int r = 0; r < 4; ++r) {
        int rowg = row0 + m * 16 + l4 * 4 + r;
        size_t oi = ((size_t)(b * SQ + rowg)) * CDIM + col;
        out[oi] = acc2[m][nt][r] + bov + hs[oi];
      }
    }
  }
}

extern "C" void kernel_launch(void* const* d_in, const int* in_sizes, int n_in,
                              void* d_out, int out_size, void* d_ws, size_t ws_size,
                              hipStream_t stream) {
  const float* hs  = (const float*)d_in[0];
  const float* ehs = (const float*)d_in[1];
  const float* Wq  = (const float*)d_in[2];
  const float* Wk  = (const float*)d_in[3];
  const float* Wv  = (const float*)d_in[4];
  const float* Wo  = (const float*)d_in[5];
  const float* bo  = (const float*)d_in[6];
  const int*   ts  = (const int*)d_in[7];
  float* out = (float*)d_out;

  char* ws = (char*)d_ws;
  float*  Kws = (float*)(ws + K_OFF);
  float*  Vws = (float*)(ws + V_OFF);
  ushort* Afr = (ushort*)(ws + A_OFF);
  ushort* Cfr = (ushort*)(ws + C_OFF);

  kv_proj<<<160, 320, 0, stream>>>(ehs, Wk, Wv, ts, Kws, Vws);
  build_A<<<32, 320, 0, stream>>>(Kws, Wq, Afr);
  build_C<<<32, 320, 0, stream>>>(Vws, Wo, Cfr);
  attn_main<<<1024, 256, 0, stream>>>(hs, Afr, Cfr, bo, out);
}